// Round 5
// baseline (184.138 us; speedup 1.0000x reference)
//
#include <hip/hip_runtime.h>
#include <hip/hip_cooperative_groups.h>
#include <stdint.h>

namespace cg = cooperative_groups;

#define N 4096
#define D 1024
#define MARGIN 0.1f
#define BM 128
#define BN 128
#define BK 64
#define NTILES ((N / BM) * (N / BN))  // 1024

typedef __attribute__((ext_vector_type(8))) __bf16 bf16x8;
typedef __attribute__((ext_vector_type(4))) __bf16 bf16x4;
typedef __attribute__((ext_vector_type(4))) float f32x4;

// Persistent cooperative kernel. Phase 1: normalize rows -> bf16 (+fp32 diag,
// +zero d_out), rows strided over all waves. grid.sync(). Phase 2: 128x128
// bf16 MFMA GEMM tiles strided over blocks, XOR-swizzled LDS (R2: conflicts
// == 0), fused loss epilogue, one atomicAdd per tile.
// R4 failure: cooperative launch rejected at 1024 blocks (fused kernel's
// VGPRs likely >128 -> 3 blocks/CU co-residency < grid). Fix:
// __launch_bounds__(256,4) caps VGPR at 128, and host queries occupancy and
// sizes the grid to a divisor of NTILES that is actually co-residable.
__global__ __launch_bounds__(256, 4) void fused_loss_kernel(
    const float* __restrict__ W, const float* __restrict__ O,
    __bf16* __restrict__ Wn, __bf16* __restrict__ On,
    float* __restrict__ dvec, float* __restrict__ out) {
  __shared__ __bf16 ldsA[BM * BK];  // 16 KB
  __shared__ __bf16 ldsB[BN * BK];  // 16 KB
  const int t = threadIdx.x;
  const int wv = t >> 6, ln = t & 63;

  // ---------------- Phase 1: prep (one wave per row, strided) -----------
  {
    const int waveStride = gridDim.x * 4;
    for (int row = blockIdx.x * 4 + wv; row < N; row += waveStride) {
      const float4* Wr = (const float4*)(W + (size_t)row * D);
      const float4* Or = (const float4*)(O + (size_t)row * D);
      float4 w[4], o[4];
      float sw = 0.f, so = 0.f, sd = 0.f;
      #pragma unroll
      for (int c = 0; c < 4; ++c) {
        w[c] = Wr[ln + c * 64];
        o[c] = Or[ln + c * 64];
        sw += w[c].x * w[c].x + w[c].y * w[c].y + w[c].z * w[c].z + w[c].w * w[c].w;
        so += o[c].x * o[c].x + o[c].y * o[c].y + o[c].z * o[c].z + o[c].w * o[c].w;
        sd += w[c].x * o[c].x + w[c].y * o[c].y + w[c].z * o[c].z + w[c].w * o[c].w;
      }
      #pragma unroll
      for (int off = 1; off < 64; off <<= 1) {
        sw += __shfl_xor(sw, off, 64);
        so += __shfl_xor(so, off, 64);
        sd += __shfl_xor(sd, off, 64);
      }
      const float inw = 1.0f / sqrtf(sw);
      const float ino = 1.0f / sqrtf(so);
      if (ln == 0) dvec[row] = sd * inw * ino;
      bf16x4* Wo = (bf16x4*)(Wn + (size_t)row * D);
      bf16x4* Oo = (bf16x4*)(On + (size_t)row * D);
      #pragma unroll
      for (int c = 0; c < 4; ++c) {
        bf16x4 vw, vo;
        vw.x = (__bf16)(w[c].x * inw); vw.y = (__bf16)(w[c].y * inw);
        vw.z = (__bf16)(w[c].z * inw); vw.w = (__bf16)(w[c].w * inw);
        vo.x = (__bf16)(o[c].x * ino); vo.y = (__bf16)(o[c].y * ino);
        vo.z = (__bf16)(o[c].z * ino); vo.w = (__bf16)(o[c].w * ino);
        Wo[ln + c * 64] = vw;
        Oo[ln + c * 64] = vo;
      }
    }
    if (blockIdx.x == 0 && t == 0) *out = 0.0f;  // d_out is poisoned each call
  }

  cg::this_grid().sync();  // device-scope: Wn/On/dvec/out visible across XCDs

  // ---------------- Phase 2: GEMM tiles (persistent, strided) -----------
  const int wm = wv >> 1, wn = wv & 1;   // 2x2 wave grid, 64x64 per wave
  const int lrow = ln & 15;
  const int quad = ln >> 4;
  const int l7 = lrow & 7;

  for (int tile = blockIdx.x; tile < NTILES; tile += gridDim.x) {
    const int bx = tile & 31, by = tile >> 5;
    f32x4 acc[4][4] = {};

    const __bf16* Ag = Wn + (size_t)(by * BM) * D;
    const __bf16* Bg = On + (size_t)(bx * BN) * D;

    for (int kt = 0; kt < D / BK; ++kt) {
      #pragma unroll
      for (int c = 0; c < 4; ++c) {
        const int e = c * 2048 + t * 8;        // LDS element slot (fixed by lane)
        const int r = e >> 6;                  // tile row
        const int chunk_l = (e >> 3) & 7;      // LDS chunk slot within row
        const int col = (chunk_l ^ (r & 7)) * 8;  // swizzled global chunk
        __builtin_amdgcn_global_load_lds(
            (const __attribute__((address_space(1))) void*)(Ag + (size_t)r * D + kt * BK + col),
            (__attribute__((address_space(3))) void*)(ldsA + e), 16, 0, 0);
        __builtin_amdgcn_global_load_lds(
            (const __attribute__((address_space(1))) void*)(Bg + (size_t)r * D + kt * BK + col),
            (__attribute__((address_space(3))) void*)(ldsB + e), 16, 0, 0);
      }
      __syncthreads();
      #pragma unroll
      for (int kk = 0; kk < BK; kk += 32) {
        const int kb = kk >> 3;
        bf16x8 af[4], bfr[4];
        #pragma unroll
        for (int mi = 0; mi < 4; ++mi) {
          const int rr = wm * 64 + mi * 16 + lrow;
          af[mi] = *(const bf16x8*)(ldsA + rr * BK + (((quad + kb) ^ l7) << 3));
        }
        #pragma unroll
        for (int ni = 0; ni < 4; ++ni) {
          const int cc = wn * 64 + ni * 16 + lrow;
          bfr[ni] = *(const bf16x8*)(ldsB + cc * BK + (((quad + kb) ^ l7) << 3));
        }
        #pragma unroll
        for (int mi = 0; mi < 4; ++mi)
          #pragma unroll
          for (int ni = 0; ni < 4; ++ni)
            acc[mi][ni] = __builtin_amdgcn_mfma_f32_16x16x32_bf16(
                af[mi], bfr[ni], acc[mi][ni], 0, 0, 0);
      }
      __syncthreads();
    }

    // Epilogue: C/D layout col=lane&15, row=quad*4+reg (verified m89/m91)
    float lsum = 0.0f;
    #pragma unroll
    for (int mi = 0; mi < 4; ++mi) {
      const int gibase = by * BM + wm * 64 + mi * 16 + quad * 4;
      #pragma unroll
      for (int r = 0; r < 4; ++r) {
        const int gi = gibase + r;
        const float di = dvec[gi];  // fp32 diagonal (accurate)
        #pragma unroll
        for (int ni = 0; ni < 4; ++ni) {
          const int gj = bx * BN + wn * 64 + ni * 16 + lrow;
          const float s = acc[mi][ni][r];
          lsum += (gi == gj) ? (1.0f - s) : fmaxf(MARGIN - s + di, 0.0f);
        }
      }
    }
    #pragma unroll
    for (int off = 32; off; off >>= 1) lsum += __shfl_down(lsum, off, 64);
    __shared__ float bsum[4];
    if (ln == 0) bsum[wv] = lsum;
    __syncthreads();
    if (t == 0) {
      const float tot = (bsum[0] + bsum[1] + bsum[2] + bsum[3]) *
                        (1.0f / ((float)N * (float)N));
      atomicAdd(out, tot);
    }
    __syncthreads();  // bsum reuse safety across persistent iterations
  }
}

extern "C" void kernel_launch(void* const* d_in, const int* in_sizes, int n_in,
                              void* d_out, int out_size, void* d_ws, size_t ws_size,
                              hipStream_t stream) {
  const float* W = (const float*)d_in[0];  // wsi_embeddings (N,1,D)
  const float* O = (const float*)d_in[1];  // omic_embeddings (N,1,D)
  __bf16* Wn = (__bf16*)d_ws;                       // 8 MB
  __bf16* On = Wn + (size_t)N * D;                  // 8 MB
  float* dvec = (float*)(On + (size_t)N * D);       // 16 KB
  float* out = (float*)d_out;

  // Size the cooperative grid to what is actually co-residable, using a
  // divisor of NTILES (1024) to avoid straggler rounds: 1024 / 512 / 256.
  int bpc = 0;
  if (hipOccupancyMaxActiveBlocksPerMultiprocessor(
          &bpc, fused_loss_kernel, 256, 0) != hipSuccess || bpc < 1)
    bpc = 1;
  const int grid = (bpc >= 4) ? 1024 : (bpc >= 2) ? 512 : 256;

  void* args[] = {(void*)&W, (void*)&O, (void*)&Wn, (void*)&On,
                  (void*)&dvec, (void*)&out};
  hipLaunchCooperativeKernel((void*)fused_loss_kernel, dim3(grid),
                             dim3(256), args, 0, stream);
}

// Round 6
// 123.744 us; speedup vs baseline: 1.4881x; 1.4881x over previous
//
#include <hip/hip_runtime.h>
#include <stdint.h>

#define N 4096
#define D 1024
#define MARGIN 0.1f
#define BM 128
#define BN 128
#define BK 64

typedef __attribute__((ext_vector_type(8))) __bf16 bf16x8;
typedef __attribute__((ext_vector_type(4))) __bf16 bf16x4;
typedef __attribute__((ext_vector_type(4))) float f32x4;

// Kernel 1: one wave per row (4 rows/block). fp32 norms + diagonal dot,
// butterfly shfl_xor reduction, write normalized bf16 rows. Block 0 also
// zeroes d_out (replaces the hipMemsetAsync graph node).
// NOTE (R5 lesson): no min-occupancy launch_bounds anywhere — gfx950's
// unified VGPR/AGPR file means the GEMM's 64-AGPR accumulator + ~88 arch
// VGPRs = 152 regs -> 3 blocks/CU. Forcing 4 strangles codegen (64 VGPR,
// 2.6x slower K-loop). 3-blocks/CU non-cooperative is the proven optimum.
__global__ __launch_bounds__(256) void prep_kernel(
    const float* __restrict__ W, const float* __restrict__ O,
    __bf16* __restrict__ Wn, __bf16* __restrict__ On,
    float* __restrict__ dvec, float* __restrict__ out) {
  const int wv = threadIdx.x >> 6, ln = threadIdx.x & 63;
  const int row = blockIdx.x * 4 + wv;
  if (blockIdx.x == 0 && threadIdx.x == 0) *out = 0.0f;  // d_out re-poisoned each call
  const float4* Wr = (const float4*)(W + (size_t)row * D);
  const float4* Or = (const float4*)(O + (size_t)row * D);
  float4 w[4], o[4];
  float sw = 0.f, so = 0.f, sd = 0.f;
  #pragma unroll
  for (int c = 0; c < 4; ++c) {
    w[c] = Wr[ln + c * 64];
    o[c] = Or[ln + c * 64];
    sw += w[c].x * w[c].x + w[c].y * w[c].y + w[c].z * w[c].z + w[c].w * w[c].w;
    so += o[c].x * o[c].x + o[c].y * o[c].y + o[c].z * o[c].z + o[c].w * o[c].w;
    sd += w[c].x * o[c].x + w[c].y * o[c].y + w[c].z * o[c].z + w[c].w * o[c].w;
  }
  #pragma unroll
  for (int off = 1; off < 64; off <<= 1) {
    sw += __shfl_xor(sw, off, 64);
    so += __shfl_xor(so, off, 64);
    sd += __shfl_xor(sd, off, 64);
  }
  const float inw = 1.0f / sqrtf(sw);
  const float ino = 1.0f / sqrtf(so);
  if (ln == 0) dvec[row] = sd * inw * ino;
  bf16x4* Wo = (bf16x4*)(Wn + (size_t)row * D);
  bf16x4* Oo = (bf16x4*)(On + (size_t)row * D);
  #pragma unroll
  for (int c = 0; c < 4; ++c) {
    bf16x4 vw, vo;
    vw.x = (__bf16)(w[c].x * inw); vw.y = (__bf16)(w[c].y * inw);
    vw.z = (__bf16)(w[c].z * inw); vw.w = (__bf16)(w[c].w * inw);
    vo.x = (__bf16)(o[c].x * ino); vo.y = (__bf16)(o[c].y * ino);
    vo.z = (__bf16)(o[c].z * ino); vo.w = (__bf16)(o[c].w * ino);
    Wo[ln + c * 64] = vw;
    Oo[ln + c * 64] = vo;
  }
}

// Kernel 2: EXACT R2 GEMM (proven 55.3 us, VGPR 88, SQ_LDS_BANK_CONFLICT 0).
// 128x128 bf16 MFMA tiles, XOR-swizzled LDS staging via global_load_lds
// width=16, fused contrastive-loss epilogue, one atomicAdd per block.
__global__ __launch_bounds__(256) void gemm_loss_kernel(
    const __bf16* __restrict__ Wn, const __bf16* __restrict__ On,
    const float* __restrict__ dvec, float* __restrict__ out) {
  __shared__ __bf16 ldsA[BM * BK];  // 16 KB
  __shared__ __bf16 ldsB[BN * BK];  // 16 KB
  const int bx = blockIdx.x, by = blockIdx.y;
  const int t = threadIdx.x;
  const int wv = t >> 6, ln = t & 63;
  const int wm = wv >> 1, wn = wv & 1;   // 2x2 wave grid, 64x64 per wave
  const int lrow = ln & 15;
  const int quad = ln >> 4;
  const int l7 = lrow & 7;

  f32x4 acc[4][4] = {};

  const __bf16* Ag = Wn + (size_t)(by * BM) * D;
  const __bf16* Bg = On + (size_t)(bx * BN) * D;

  for (int kt = 0; kt < D / BK; ++kt) {
    #pragma unroll
    for (int c = 0; c < 4; ++c) {
      const int e = c * 2048 + t * 8;        // LDS element slot (fixed by lane)
      const int r = e >> 6;                  // tile row
      const int chunk_l = (e >> 3) & 7;      // LDS chunk slot within row
      const int col = (chunk_l ^ (r & 7)) * 8;  // swizzled global chunk
      __builtin_amdgcn_global_load_lds(
          (const __attribute__((address_space(1))) void*)(Ag + (size_t)r * D + kt * BK + col),
          (__attribute__((address_space(3))) void*)(ldsA + e), 16, 0, 0);
      __builtin_amdgcn_global_load_lds(
          (const __attribute__((address_space(1))) void*)(Bg + (size_t)r * D + kt * BK + col),
          (__attribute__((address_space(3))) void*)(ldsB + e), 16, 0, 0);
    }
    __syncthreads();
    #pragma unroll
    for (int kk = 0; kk < BK; kk += 32) {
      const int kb = kk >> 3;
      bf16x8 af[4], bfr[4];
      #pragma unroll
      for (int mi = 0; mi < 4; ++mi) {
        const int rr = wm * 64 + mi * 16 + lrow;
        af[mi] = *(const bf16x8*)(ldsA + rr * BK + (((quad + kb) ^ l7) << 3));
      }
      #pragma unroll
      for (int ni = 0; ni < 4; ++ni) {
        const int cc = wn * 64 + ni * 16 + lrow;
        bfr[ni] = *(const bf16x8*)(ldsB + cc * BK + (((quad + kb) ^ l7) << 3));
      }
      #pragma unroll
      for (int mi = 0; mi < 4; ++mi)
        #pragma unroll
        for (int ni = 0; ni < 4; ++ni)
          acc[mi][ni] = __builtin_amdgcn_mfma_f32_16x16x32_bf16(
              af[mi], bfr[ni], acc[mi][ni], 0, 0, 0);
    }
    __syncthreads();
  }

  // Epilogue: C/D layout col=lane&15, row=quad*4+reg (verified m89/m91)
  float lsum = 0.0f;
  #pragma unroll
  for (int mi = 0; mi < 4; ++mi) {
    const int gibase = by * BM + wm * 64 + mi * 16 + quad * 4;
    #pragma unroll
    for (int r = 0; r < 4; ++r) {
      const int gi = gibase + r;
      const float di = dvec[gi];  // fp32 diagonal (accurate)
      #pragma unroll
      for (int ni = 0; ni < 4; ++ni) {
        const int gj = bx * BN + wn * 64 + ni * 16 + lrow;
        const float s = acc[mi][ni][r];
        lsum += (gi == gj) ? (1.0f - s) : fmaxf(MARGIN - s + di, 0.0f);
      }
    }
  }
  #pragma unroll
  for (int off = 32; off; off >>= 1) lsum += __shfl_down(lsum, off, 64);
  __shared__ float bsum[4];
  if (ln == 0) bsum[wv] = lsum;
  __syncthreads();
  if (t == 0) {
    const float tot = (bsum[0] + bsum[1] + bsum[2] + bsum[3]) *
                      (1.0f / ((float)N * (float)N));
    atomicAdd(out, tot);
  }
}

extern "C" void kernel_launch(void* const* d_in, const int* in_sizes, int n_in,
                              void* d_out, int out_size, void* d_ws, size_t ws_size,
                              hipStream_t stream) {
  const float* W = (const float*)d_in[0];  // wsi_embeddings (N,1,D)
  const float* O = (const float*)d_in[1];  // omic_embeddings (N,1,D)
  __bf16* Wn = (__bf16*)d_ws;                       // 8 MB
  __bf16* On = Wn + (size_t)N * D;                  // 8 MB
  float* dvec = (float*)(On + (size_t)N * D);       // 16 KB
  float* out = (float*)d_out;

  prep_kernel<<<N / 4, 256, 0, stream>>>(W, O, Wn, On, dvec, out);
  dim3 grid(N / BN, N / BM);
  gemm_loss_kernel<<<grid, 256, 0, stream>>>(Wn, On, dvec, out);
}